// Round 1
// baseline (1852.137 us; speedup 1.0000x reference)
//
#include <hip/hip_runtime.h>

// APPNP: K steps of D^{-1/2} A D^{-1/2} propagation + teleport, then MLP.
// Strategy: build dst-CSR once per call (histogram + 1-block scan + scatter),
// fold (1-alpha)*norm[src]*norm[dst] into a per-edge weight, then 10 pull-mode
// atomic-free gather steps, then a fused LDS-tiled MLP.

#define N_NODES 100000
#define N_EDGES 800000
#define D_DATA  100
#define H_DIM   256
#define N_CLS   47
#define K_STEPS 10
#define ALPHA   0.1f

// ---------------- CSR build ----------------

__global__ void deg_kernel(const int* __restrict__ dst, int* __restrict__ deg, int e) {
    int i = blockIdx.x * blockDim.x + threadIdx.x;
    if (i < e) atomicAdd(&deg[dst[i]], 1);
}

// Single-block exclusive scan of deg -> row_ptr, plus norm = rsqrt(max(deg,1)).
__global__ void scan_norm_kernel(const int* __restrict__ deg,
                                 int* __restrict__ row_ptr,
                                 float* __restrict__ norm, int n) {
    __shared__ int sums[1024];
    int tid = threadIdx.x;
    int chunk = (n + 1023) / 1024;
    int beg = tid * chunk;
    int end = min(beg + chunk, n);
    int s = 0;
    for (int i = beg; i < end; ++i) s += deg[i];
    sums[tid] = s;
    __syncthreads();
    // Hillis-Steele inclusive scan over the 1024 partial sums.
    for (int off = 1; off < 1024; off <<= 1) {
        int v = (tid >= off) ? sums[tid - off] : 0;
        __syncthreads();
        sums[tid] += v;
        __syncthreads();
    }
    int prefix = (tid > 0) ? sums[tid - 1] : 0;
    for (int i = beg; i < end; ++i) {
        row_ptr[i] = prefix;
        int d = deg[i];
        norm[i] = rsqrtf((float)max(d, 1));
        prefix += d;
    }
    if (tid == 1023) row_ptr[n] = sums[1023];
}

// Scatter edges into CSR slots; pack (weight, src) into a float2 for one 8B load.
__global__ void scatter_kernel(const int* __restrict__ src, const int* __restrict__ dst,
                               const float* __restrict__ norm,
                               const int* __restrict__ row_ptr, int* __restrict__ fill,
                               float2* __restrict__ ew, int e) {
    int i = blockIdx.x * blockDim.x + threadIdx.x;
    if (i < e) {
        int d = dst[i], s = src[i];
        int pos = row_ptr[d] + atomicAdd(&fill[d], 1);
        float w = (1.0f - ALPHA) * norm[s] * norm[d];
        ew[pos] = make_float2(w, __int_as_float(s));
    }
}

// ---------------- propagation ----------------
// 64 lanes per node; lane l owns feature l, and feature l+64 if l < 36.
// h_out[n] = sum_e w_e * h_in[src_e] + alpha * x[n]

__global__ void prop_kernel(const float* __restrict__ hin,
                            const float* __restrict__ x,
                            const int* __restrict__ row_ptr,
                            const float2* __restrict__ ew,
                            float* __restrict__ hout, int n_nodes) {
    int lane = threadIdx.x & 63;
    int node = blockIdx.x * (blockDim.x >> 6) + (threadIdx.x >> 6);
    if (node >= n_nodes) return;
    int beg = row_ptr[node];
    int end = row_ptr[node + 1];
    float acc0 = 0.f, acc1 = 0.f;
    for (int e = beg; e < end; ++e) {
        float2 p = ew[e];                      // broadcast within the wave
        int s = __float_as_int(p.y);
        const float* hr = hin + s * D_DATA;
        acc0 += p.x * hr[lane];
        if (lane < D_DATA - 64) acc1 += p.x * hr[64 + lane];
    }
    int o = node * D_DATA;
    hout[o + lane] = acc0 + ALPHA * x[o + lane];
    if (lane < D_DATA - 64) hout[o + 64 + lane] = acc1 + ALPHA * x[o + 64 + lane];
}

// ---------------- fused MLP ----------------
// Block = 256 threads, 32 nodes. Phase 1: thread j owns hidden column j,
// register-blocks 32 nodes so W1 is read exactly once per block.
// Phase 2: z tile (LDS) @ W2 -> logits.

#define TN 32

__global__ void mlp_kernel(const float* __restrict__ h,
                           const float* __restrict__ W1, const float* __restrict__ b1,
                           const float* __restrict__ W2, const float* __restrict__ b2,
                           float* __restrict__ out, int n_nodes) {
    __shared__ float hs[TN][D_DATA];   // 12.8 KB
    __shared__ float zs[TN][H_DIM];    // 32 KB
    int node0 = blockIdx.x * TN;

    for (int i = threadIdx.x; i < TN * D_DATA; i += blockDim.x) {
        int n = i / D_DATA, d = i - n * D_DATA;
        int gn = node0 + n;
        hs[n][d] = (gn < n_nodes) ? h[gn * D_DATA + d] : 0.f;
    }
    __syncthreads();

    // phase 1: z = relu(h @ W1 + b1)
    {
        int j = threadIdx.x;               // 0..255 == H_DIM
        float acc[TN];
        float bj = b1[j];
#pragma unroll
        for (int i = 0; i < TN; ++i) acc[i] = bj;
        for (int d = 0; d < D_DATA; ++d) {
            float w = W1[d * H_DIM + j];   // coalesced; read once per block
#pragma unroll
            for (int i = 0; i < TN; ++i) acc[i] += hs[i][d] * w;
        }
#pragma unroll
        for (int i = 0; i < TN; ++i) zs[i][j] = fmaxf(acc[i], 0.f);
    }
    __syncthreads();

    // phase 2: out = z @ W2 + b2
    for (int o = threadIdx.x; o < TN * N_CLS; o += blockDim.x) {
        int i = o / N_CLS, c = o - i * N_CLS;
        int gn = node0 + i;
        if (gn >= n_nodes) continue;
        float a = b2[c];
        for (int j = 0; j < H_DIM; ++j) a += zs[i][j] * W2[j * N_CLS + c];
        out[gn * N_CLS + c] = a;
    }
}

// ---------------- launch ----------------

static inline size_t align_up(size_t v, size_t a) { return (v + a - 1) & ~(a - 1); }

extern "C" void kernel_launch(void* const* d_in, const int* in_sizes, int n_in,
                              void* d_out, int out_size, void* d_ws, size_t ws_size,
                              hipStream_t stream) {
    const float* x   = (const float*)d_in[0];
    const int*   src = (const int*)d_in[1];
    const int*   dst = (const int*)d_in[2];
    const float* W1  = (const float*)d_in[3];
    const float* b1  = (const float*)d_in[4];
    const float* W2  = (const float*)d_in[5];
    const float* b2  = (const float*)d_in[6];
    float* out = (float*)d_out;

    // workspace carve-up
    char* p = (char*)d_ws;
    size_t off = 0;
    int* deg = (int*)(p + off);           off = align_up(off + N_NODES * 4, 256);
    int* row_ptr = (int*)(p + off);       off = align_up(off + (N_NODES + 1) * 4, 256);
    int* fill = (int*)(p + off);          off = align_up(off + N_NODES * 4, 256);
    float* norm = (float*)(p + off);      off = align_up(off + N_NODES * 4, 256);
    float2* ew = (float2*)(p + off);      off = align_up(off + N_EDGES * 8, 256);
    float* hA = (float*)(p + off);        off = align_up(off + (size_t)N_NODES * D_DATA * 4, 256);
    float* hB = (float*)(p + off);        off = align_up(off + (size_t)N_NODES * D_DATA * 4, 256);
    (void)ws_size;

    hipMemsetAsync(deg, 0, N_NODES * 4, stream);
    hipMemsetAsync(fill, 0, N_NODES * 4, stream);

    int eb = (N_EDGES + 255) / 256;
    deg_kernel<<<eb, 256, 0, stream>>>(dst, deg, N_EDGES);
    scan_norm_kernel<<<1, 1024, 0, stream>>>(deg, row_ptr, norm, N_NODES);
    scatter_kernel<<<eb, 256, 0, stream>>>(src, dst, norm, row_ptr, fill, ew, N_EDGES);

    // propagation: 4 nodes per 256-thread block
    int pb = (N_NODES + 3) / 4;
    const float* hin = x;
    float* houts[2] = {hA, hB};
    for (int k = 0; k < K_STEPS; ++k) {
        float* ho = houts[k & 1];
        prop_kernel<<<pb, 256, 0, stream>>>(hin, x, row_ptr, ew, ho, N_NODES);
        hin = ho;
    }

    // fused MLP on final h (hin)
    int mb = (N_NODES + TN - 1) / TN;
    mlp_kernel<<<mb, 256, 0, stream>>>(hin, W1, b1, W2, b2, out, N_NODES);
}

// Round 2
// 1398.981 us; speedup vs baseline: 1.3239x; 1.3239x over previous
//
#include <hip/hip_runtime.h>

// APPNP: K steps of D^{-1/2} A D^{-1/2} propagation + teleport, then MLP.
// CSR built once per call (histogram + 1-block scan + scatter); per-edge
// weight folds (1-alpha)*norm[src]*norm[dst]. Propagation is pull-mode,
// atomic-free, unrolled x4 for memory-level parallelism. MLP is register-
// tiled with float4 LDS traffic and a pre-transposed W2.

#define N_NODES 100000
#define N_EDGES 800000
#define D_DATA  100
#define H_DIM   256
#define N_CLS   47
#define K_STEPS 10
#define ALPHA   0.1f

// ---------------- CSR build ----------------

__global__ void deg_kernel(const int* __restrict__ dst, int* __restrict__ deg, int e) {
    int i = blockIdx.x * blockDim.x + threadIdx.x;
    if (i < e) atomicAdd(&deg[dst[i]], 1);
}

// Single-block exclusive scan of deg -> row_ptr, plus norm = rsqrt(max(deg,1)).
__global__ void scan_norm_kernel(const int* __restrict__ deg,
                                 int* __restrict__ row_ptr,
                                 float* __restrict__ norm, int n) {
    __shared__ int sums[1024];
    int tid = threadIdx.x;
    int chunk = (n + 1023) / 1024;
    int beg = tid * chunk;
    int end = min(beg + chunk, n);
    int s = 0;
    for (int i = beg; i < end; ++i) s += deg[i];
    sums[tid] = s;
    __syncthreads();
    for (int off = 1; off < 1024; off <<= 1) {
        int v = (tid >= off) ? sums[tid - off] : 0;
        __syncthreads();
        sums[tid] += v;
        __syncthreads();
    }
    int prefix = (tid > 0) ? sums[tid - 1] : 0;
    for (int i = beg; i < end; ++i) {
        row_ptr[i] = prefix;
        int d = deg[i];
        norm[i] = rsqrtf((float)max(d, 1));
        prefix += d;
    }
    if (tid == 1023) row_ptr[n] = sums[1023];
}

__global__ void scatter_kernel(const int* __restrict__ src, const int* __restrict__ dst,
                               const float* __restrict__ norm,
                               const int* __restrict__ row_ptr, int* __restrict__ fill,
                               float2* __restrict__ ew, int e) {
    int i = blockIdx.x * blockDim.x + threadIdx.x;
    if (i < e) {
        int d = dst[i], s = src[i];
        int pos = row_ptr[d] + atomicAdd(&fill[d], 1);
        float w = (1.0f - ALPHA) * norm[s] * norm[d];
        ew[pos] = make_float2(w, __int_as_float(s));
    }
}

// W2 [256][47] -> W2t [48][256], zero-padded col 47. Runs after scatter; reuses
// the (dead) fill buffer as output.
__global__ void transpose_w2_kernel(const float* __restrict__ W2, float* __restrict__ W2t) {
    int idx = blockIdx.x * blockDim.x + threadIdx.x;
    if (idx < 48 * H_DIM) {
        int c = idx >> 8;           // 0..47
        int j = idx & (H_DIM - 1);  // 0..255
        W2t[c * H_DIM + j] = (c < N_CLS) ? W2[j * N_CLS + c] : 0.f;
    }
}

// ---------------- propagation ----------------
// One wave per node; lane l owns features l and l+64 (l<36). Edge loop
// unrolled x4 so 4 independent h-row gathers are in flight per wave.

__global__ __launch_bounds__(256) void prop_kernel(
        const float* __restrict__ hin, const float* __restrict__ x,
        const int* __restrict__ row_ptr, const float2* __restrict__ ew,
        float* __restrict__ hout, int n_nodes) {
    int lane = threadIdx.x & 63;
    int node = blockIdx.x * (blockDim.x >> 6) + (threadIdx.x >> 6);
    if (node >= n_nodes) return;
    int beg = row_ptr[node];
    int end = row_ptr[node + 1];
    bool hi = lane < (D_DATA - 64);   // 36 lanes carry the second feature half
    float a0 = 0.f, a1 = 0.f, b0 = 0.f, b1 = 0.f;
    float c0 = 0.f, c1 = 0.f, d0 = 0.f, d1 = 0.f;
    int e = beg;
    for (; e + 4 <= end; e += 4) {
        float2 p0 = ew[e], p1 = ew[e + 1], p2 = ew[e + 2], p3 = ew[e + 3];
        const float* r0 = hin + (size_t)__float_as_int(p0.y) * D_DATA;
        const float* r1 = hin + (size_t)__float_as_int(p1.y) * D_DATA;
        const float* r2 = hin + (size_t)__float_as_int(p2.y) * D_DATA;
        const float* r3 = hin + (size_t)__float_as_int(p3.y) * D_DATA;
        float v0 = r0[lane], v1 = r1[lane], v2 = r2[lane], v3 = r3[lane];
        float u0 = 0.f, u1 = 0.f, u2 = 0.f, u3 = 0.f;
        if (hi) {
            u0 = r0[64 + lane]; u1 = r1[64 + lane];
            u2 = r2[64 + lane]; u3 = r3[64 + lane];
        }
        a0 += p0.x * v0; b0 += p1.x * v1; c0 += p2.x * v2; d0 += p3.x * v3;
        a1 += p0.x * u0; b1 += p1.x * u1; c1 += p2.x * u2; d1 += p3.x * u3;
    }
    for (; e < end; ++e) {
        float2 p = ew[e];
        const float* r = hin + (size_t)__float_as_int(p.y) * D_DATA;
        a0 += p.x * r[lane];
        if (hi) a1 += p.x * r[64 + lane];
    }
    float s0 = (a0 + b0) + (c0 + d0);
    float s1 = (a1 + b1) + (c1 + d1);
    int o = node * D_DATA;
    hout[o + lane] = s0 + ALPHA * x[o + lane];
    if (hi) hout[o + 64 + lane] = s1 + ALPHA * x[o + 64 + lane];
}

// ---------------- fused MLP ----------------
// Block = 256 threads, 32 nodes (100000 % 32 == 0 -> no tail).
// Phase 1: thread (cg = t&63, ng = t>>6) owns an 8-node x 4-col register tile;
//   float4 LDS reads of h, float4 global reads of W1 -> 128 FMA per 12 loads.
// Phase 2: thread (cg2 = t&15 -> 3 cols, ng2 = t>>4 -> 2 nodes); float4 reads
//   of padded zs rows and pre-transposed W2t.

#define TN 32
#define HP (H_DIM + 8)   // pad zs rows: 264 % 32 == 8 breaks bank alignment

__global__ __launch_bounds__(256) void mlp_kernel(
        const float* __restrict__ h,
        const float* __restrict__ W1, const float* __restrict__ b1,
        const float* __restrict__ W2t, const float* __restrict__ b2,
        float* __restrict__ out, int n_nodes) {
    __shared__ float hs[TN][D_DATA];   // 12.8 KB, rows 400 B (16B-aligned)
    __shared__ float zs[TN][HP];       // 33.8 KB
    int tid = threadIdx.x;
    int node0 = blockIdx.x * TN;

    {   // stage 32 contiguous h rows (3200 floats) as float4
        const float4* src4 = (const float4*)(h + (size_t)node0 * D_DATA);
        float4* hs4 = (float4*)&hs[0][0];
        for (int i = tid; i < TN * D_DATA / 4; i += blockDim.x) hs4[i] = src4[i];
    }
    __syncthreads();

    // ---- phase 1: z = relu(h @ W1 + b1) ----
    {
        int cg = tid & 63;   // 4 cols: 4*cg..4*cg+3
        int ng = tid >> 6;   // 8 nodes: 8*ng..8*ng+7
        float acc[8][4];
        float4 bv = *(const float4*)(b1 + 4 * cg);
#pragma unroll
        for (int i = 0; i < 8; ++i) {
            acc[i][0] = bv.x; acc[i][1] = bv.y; acc[i][2] = bv.z; acc[i][3] = bv.w;
        }
        for (int d4 = 0; d4 < D_DATA / 4; ++d4) {
            float hv[8][4];
#pragma unroll
            for (int i = 0; i < 8; ++i) {
                float4 t = *(const float4*)&hs[ng * 8 + i][d4 * 4];
                hv[i][0] = t.x; hv[i][1] = t.y; hv[i][2] = t.z; hv[i][3] = t.w;
            }
            float wv[4][4];
#pragma unroll
            for (int k = 0; k < 4; ++k) {
                float4 t = *(const float4*)&W1[(size_t)(d4 * 4 + k) * H_DIM + 4 * cg];
                wv[k][0] = t.x; wv[k][1] = t.y; wv[k][2] = t.z; wv[k][3] = t.w;
            }
#pragma unroll
            for (int k = 0; k < 4; ++k)
#pragma unroll
                for (int i = 0; i < 8; ++i)
#pragma unroll
                    for (int c = 0; c < 4; ++c)
                        acc[i][c] += hv[i][k] * wv[k][c];
        }
#pragma unroll
        for (int i = 0; i < 8; ++i) {
            float4 t;
            t.x = fmaxf(acc[i][0], 0.f); t.y = fmaxf(acc[i][1], 0.f);
            t.z = fmaxf(acc[i][2], 0.f); t.w = fmaxf(acc[i][3], 0.f);
            *(float4*)&zs[ng * 8 + i][4 * cg] = t;
        }
    }
    __syncthreads();

    // ---- phase 2: out = z @ W2 + b2 ----
    {
        int cg2 = tid & 15;   // 3 cols: 3*cg2..3*cg2+2 (covers 48, col 47 is pad)
        int ng2 = tid >> 4;   // 2 nodes: 2*ng2, 2*ng2+1
        int col0 = cg2 * 3;
        int nA = ng2 * 2, nB = nA + 1;
        float acc2[2][3];
#pragma unroll
        for (int cc = 0; cc < 3; ++cc) {
            int c = col0 + cc;
            float bb = (c < N_CLS) ? b2[c] : 0.f;
            acc2[0][cc] = bb; acc2[1][cc] = bb;
        }
        for (int j4 = 0; j4 < H_DIM / 4; ++j4) {
            float4 z0 = *(const float4*)&zs[nA][j4 * 4];
            float4 z1 = *(const float4*)&zs[nB][j4 * 4];
#pragma unroll
            for (int cc = 0; cc < 3; ++cc) {
                float4 w = *(const float4*)&W2t[(size_t)(col0 + cc) * H_DIM + j4 * 4];
                acc2[0][cc] += z0.x * w.x + z0.y * w.y + z0.z * w.z + z0.w * w.w;
                acc2[1][cc] += z1.x * w.x + z1.y * w.y + z1.z * w.z + z1.w * w.w;
            }
        }
#pragma unroll
        for (int n = 0; n < 2; ++n)
#pragma unroll
            for (int cc = 0; cc < 3; ++cc) {
                int c = col0 + cc;
                int gn = node0 + nA + n;
                if (c < N_CLS && gn < n_nodes)
                    out[(size_t)gn * N_CLS + c] = acc2[n][cc];
            }
    }
}

// ---------------- launch ----------------

static inline size_t align_up(size_t v, size_t a) { return (v + a - 1) & ~(a - 1); }

extern "C" void kernel_launch(void* const* d_in, const int* in_sizes, int n_in,
                              void* d_out, int out_size, void* d_ws, size_t ws_size,
                              hipStream_t stream) {
    const float* x   = (const float*)d_in[0];
    const int*   src = (const int*)d_in[1];
    const int*   dst = (const int*)d_in[2];
    const float* W1  = (const float*)d_in[3];
    const float* b1  = (const float*)d_in[4];
    const float* W2  = (const float*)d_in[5];
    const float* b2  = (const float*)d_in[6];
    float* out = (float*)d_out;

    char* p = (char*)d_ws;
    size_t off = 0;
    int* deg = (int*)(p + off);           off = align_up(off + N_NODES * 4, 256);
    int* row_ptr = (int*)(p + off);       off = align_up(off + (N_NODES + 1) * 4, 256);
    int* fill = (int*)(p + off);          off = align_up(off + N_NODES * 4, 256);
    float* norm = (float*)(p + off);      off = align_up(off + N_NODES * 4, 256);
    float2* ew = (float2*)(p + off);      off = align_up(off + N_EDGES * 8, 256);
    float* hA = (float*)(p + off);        off = align_up(off + (size_t)N_NODES * D_DATA * 4, 256);
    float* hB = (float*)(p + off);        off = align_up(off + (size_t)N_NODES * D_DATA * 4, 256);
    (void)ws_size;
    // fill is dead after scatter_kernel; reuse it for W2t (48*256*4 = 48 KB < 400 KB)
    float* W2t = (float*)fill;

    hipMemsetAsync(deg, 0, N_NODES * 4, stream);
    hipMemsetAsync(fill, 0, N_NODES * 4, stream);

    int eb = (N_EDGES + 255) / 256;
    deg_kernel<<<eb, 256, 0, stream>>>(dst, deg, N_EDGES);
    scan_norm_kernel<<<1, 1024, 0, stream>>>(deg, row_ptr, norm, N_NODES);
    scatter_kernel<<<eb, 256, 0, stream>>>(src, dst, norm, row_ptr, fill, ew, N_EDGES);
    transpose_w2_kernel<<<(48 * H_DIM + 255) / 256, 256, 0, stream>>>(W2, W2t);

    int pb = (N_NODES + 3) / 4;   // 4 nodes per 256-thread block
    const float* hin = x;
    float* houts[2] = {hA, hB};
    for (int k = 0; k < K_STEPS; ++k) {
        float* ho = houts[k & 1];
        prop_kernel<<<pb, 256, 0, stream>>>(hin, x, row_ptr, ew, ho, N_NODES);
        hin = ho;
    }

    int mb = N_NODES / TN;   // 100000 % 32 == 0
    mlp_kernel<<<mb, 256, 0, stream>>>(hin, W1, b1, W2t, b2, out, N_NODES);
}

// Round 3
// 1174.935 us; speedup vs baseline: 1.5764x; 1.1907x over previous
//
#include <hip/hip_runtime.h>

// APPNP: K steps of D^{-1/2} A D^{-1/2} propagation + teleport, then MLP.
// CSR built once per call; per-edge weight folds (1-alpha)*norm[src]*norm[dst].
// Propagation: pull-mode, wave-per-node, scalar (s_load) edge reads, x8 unroll
// for 16 gathers in flight. MLP: phase-1 reads h via wave-uniform scalar loads
// (no LDS h tile), software-pipelined W1; z tile in padded LDS; phase-2 cols
// grouped per 16 threads so W2t loads are 4-address broadcasts.

#define N_NODES 100000
#define N_EDGES 800000
#define D_DATA  100
#define H_DIM   256
#define N_CLS   47
#define K_STEPS 10
#define ALPHA   0.1f

// ---------------- CSR build ----------------

__global__ void deg_kernel(const int* __restrict__ dst, int* __restrict__ deg, int e) {
    int i = blockIdx.x * blockDim.x + threadIdx.x;
    if (i < e) atomicAdd(&deg[dst[i]], 1);
}

__global__ void scan_norm_kernel(const int* __restrict__ deg,
                                 int* __restrict__ row_ptr,
                                 float* __restrict__ norm, int n) {
    __shared__ int sums[1024];
    int tid = threadIdx.x;
    int chunk = (n + 1023) / 1024;
    int beg = tid * chunk;
    int end = min(beg + chunk, n);
    int s = 0;
    for (int i = beg; i < end; ++i) s += deg[i];
    sums[tid] = s;
    __syncthreads();
    for (int off = 1; off < 1024; off <<= 1) {
        int v = (tid >= off) ? sums[tid - off] : 0;
        __syncthreads();
        sums[tid] += v;
        __syncthreads();
    }
    int prefix = (tid > 0) ? sums[tid - 1] : 0;
    for (int i = beg; i < end; ++i) {
        row_ptr[i] = prefix;
        int d = deg[i];
        norm[i] = rsqrtf((float)max(d, 1));
        prefix += d;
    }
    if (tid == 1023) row_ptr[n] = sums[1023];
}

__global__ void scatter_kernel(const int* __restrict__ src, const int* __restrict__ dst,
                               const float* __restrict__ norm,
                               const int* __restrict__ row_ptr, int* __restrict__ fill,
                               float2* __restrict__ ew, int e) {
    int i = blockIdx.x * blockDim.x + threadIdx.x;
    if (i < e) {
        int d = dst[i], s = src[i];
        int pos = row_ptr[d] + atomicAdd(&fill[d], 1);
        float w = (1.0f - ALPHA) * norm[s] * norm[d];
        ew[pos] = make_float2(w, __int_as_float(s));
    }
}

// W2 [256][47] -> W2t [48][256], zero-padded col 47.
__global__ void transpose_w2_kernel(const float* __restrict__ W2, float* __restrict__ W2t) {
    int idx = blockIdx.x * blockDim.x + threadIdx.x;
    if (idx < 48 * H_DIM) {
        int c = idx >> 8;
        int j = idx & (H_DIM - 1);
        W2t[c * H_DIM + j] = (c < N_CLS) ? W2[j * N_CLS + c] : 0.f;
    }
}

// ---------------- propagation ----------------
// One wave per node (node index forced wave-uniform -> scalar row_ptr/ew
// loads). Lane l owns features l and l+64 (l<36). Main loop unrolled x8.

__global__ __launch_bounds__(256) void prop_kernel(
        const float* __restrict__ hin, const float* __restrict__ x,
        const int* __restrict__ row_ptr, const float2* __restrict__ ew,
        float* __restrict__ hout, int n_nodes) {
    int lane = threadIdx.x & 63;
    int node = __builtin_amdgcn_readfirstlane(blockIdx.x * 4 + (threadIdx.x >> 6));
    if (node >= n_nodes) return;
    int beg = __builtin_amdgcn_readfirstlane(row_ptr[node]);
    int end = __builtin_amdgcn_readfirstlane(row_ptr[node + 1]);
    bool hi = lane < (D_DATA - 64);
    float a0 = 0.f, a1 = 0.f, b0 = 0.f, b1 = 0.f;
    float c0 = 0.f, c1 = 0.f, d0 = 0.f, d1 = 0.f;
    int e = beg;
    for (; e + 8 <= end; e += 8) {
        float2 p[8];
        const float* r[8];
#pragma unroll
        for (int j = 0; j < 8; ++j) p[j] = ew[e + j];          // uniform -> s_load
#pragma unroll
        for (int j = 0; j < 8; ++j)
            r[j] = hin + (size_t)__float_as_int(p[j].y) * D_DATA;
        float v[8], u[8];
#pragma unroll
        for (int j = 0; j < 8; ++j) v[j] = r[j][lane];
#pragma unroll
        for (int j = 0; j < 8; ++j) u[j] = hi ? r[j][64 + lane] : 0.f;
        a0 += p[0].x * v[0]; b0 += p[1].x * v[1]; c0 += p[2].x * v[2]; d0 += p[3].x * v[3];
        a0 += p[4].x * v[4]; b0 += p[5].x * v[5]; c0 += p[6].x * v[6]; d0 += p[7].x * v[7];
        a1 += p[0].x * u[0]; b1 += p[1].x * u[1]; c1 += p[2].x * u[2]; d1 += p[3].x * u[3];
        a1 += p[4].x * u[4]; b1 += p[5].x * u[5]; c1 += p[6].x * u[6]; d1 += p[7].x * u[7];
    }
    for (; e + 4 <= end; e += 4) {
        float2 p0 = ew[e], p1 = ew[e + 1], p2 = ew[e + 2], p3 = ew[e + 3];
        const float* r0 = hin + (size_t)__float_as_int(p0.y) * D_DATA;
        const float* r1 = hin + (size_t)__float_as_int(p1.y) * D_DATA;
        const float* r2 = hin + (size_t)__float_as_int(p2.y) * D_DATA;
        const float* r3 = hin + (size_t)__float_as_int(p3.y) * D_DATA;
        float v0 = r0[lane], v1 = r1[lane], v2 = r2[lane], v3 = r3[lane];
        float u0 = 0.f, u1 = 0.f, u2 = 0.f, u3 = 0.f;
        if (hi) { u0 = r0[64 + lane]; u1 = r1[64 + lane]; u2 = r2[64 + lane]; u3 = r3[64 + lane]; }
        a0 += p0.x * v0; b0 += p1.x * v1; c0 += p2.x * v2; d0 += p3.x * v3;
        a1 += p0.x * u0; b1 += p1.x * u1; c1 += p2.x * u2; d1 += p3.x * u3;
    }
    for (; e < end; ++e) {
        float2 p = ew[e];
        const float* r = hin + (size_t)__float_as_int(p.y) * D_DATA;
        a0 += p.x * r[lane];
        if (hi) a1 += p.x * r[64 + lane];
    }
    float s0 = (a0 + b0) + (c0 + d0);
    float s1 = (a1 + b1) + (c1 + d1);
    int o = node * D_DATA;
    hout[o + lane] = s0 + ALPHA * x[o + lane];
    if (hi) hout[o + 64 + lane] = s1 + ALPHA * x[o + 64 + lane];
}

// ---------------- fused MLP ----------------
// Block = 256 threads, 32 nodes. Phase 1: thread (cg=t&63 -> 4 cols,
// ng=t>>6 -> 8 nodes); h rows are wave-uniform -> forced scalar loads via
// readfirstlane; W1 chunk software-pipelined. Phase 2: thread (cg2=t>>4 ->
// 3 cols, ng2=t&15 -> 2 nodes); 4 distinct W2t addrs per wave (broadcast).

#define TN 32
#define HP 260   // 260 % 32 == 4: even bank coverage for both write & read maps

__global__ __launch_bounds__(256, 4) void mlp_kernel(
        const float* __restrict__ h,
        const float* __restrict__ W1, const float* __restrict__ b1,
        const float* __restrict__ W2t, const float* __restrict__ b2,
        float* __restrict__ out, int n_nodes) {
    __shared__ float zs[TN][HP];   // 32.5 KB -> 4 blocks/CU
    int tid = threadIdx.x;
    int node0 = blockIdx.x * TN;

    // ---- phase 1: z = relu(h @ W1 + b1) ----
    {
        int cg = tid & 63;
        int ng = tid >> 6;
        // wave-uniform h row pointers -> scalar loads
        const float4* hrow[8];
#pragma unroll
        for (int i = 0; i < 8; ++i) {
            int r = __builtin_amdgcn_readfirstlane(node0 + ng * 8 + i);
            hrow[i] = (const float4*)(h + (size_t)r * D_DATA);
        }
        float acc[8][4];
        float4 bv = *(const float4*)(b1 + 4 * cg);
#pragma unroll
        for (int i = 0; i < 8; ++i) {
            acc[i][0] = bv.x; acc[i][1] = bv.y; acc[i][2] = bv.z; acc[i][3] = bv.w;
        }
        float4 wv[4], wn[4];
#pragma unroll
        for (int k = 0; k < 4; ++k)
            wv[k] = *(const float4*)&W1[(size_t)k * H_DIM + 4 * cg];
        for (int d4 = 0; d4 < D_DATA / 4; ++d4) {
            if (d4 + 1 < D_DATA / 4) {
#pragma unroll
                for (int k = 0; k < 4; ++k)
                    wn[k] = *(const float4*)&W1[(size_t)((d4 + 1) * 4 + k) * H_DIM + 4 * cg];
            }
            float4 hv[8];
#pragma unroll
            for (int i = 0; i < 8; ++i) hv[i] = hrow[i][d4];   // scalar pipe
#pragma unroll
            for (int i = 0; i < 8; ++i) {
                acc[i][0] += hv[i].x * wv[0].x + hv[i].y * wv[1].x + hv[i].z * wv[2].x + hv[i].w * wv[3].x;
                acc[i][1] += hv[i].x * wv[0].y + hv[i].y * wv[1].y + hv[i].z * wv[2].y + hv[i].w * wv[3].y;
                acc[i][2] += hv[i].x * wv[0].z + hv[i].y * wv[1].z + hv[i].z * wv[2].z + hv[i].w * wv[3].z;
                acc[i][3] += hv[i].x * wv[0].w + hv[i].y * wv[1].w + hv[i].z * wv[2].w + hv[i].w * wv[3].w;
            }
#pragma unroll
            for (int k = 0; k < 4; ++k) wv[k] = wn[k];
        }
#pragma unroll
        for (int i = 0; i < 8; ++i) {
            float4 t;
            t.x = fmaxf(acc[i][0], 0.f); t.y = fmaxf(acc[i][1], 0.f);
            t.z = fmaxf(acc[i][2], 0.f); t.w = fmaxf(acc[i][3], 0.f);
            *(float4*)&zs[ng * 8 + i][4 * cg] = t;
        }
    }
    __syncthreads();

    // ---- phase 2: out = z @ W2 + b2 ----
    {
        int cg2 = tid >> 4;    // 16 col groups of 3; 4 distinct per wave
        int ng2 = tid & 15;    // 16 node pairs
        int col0 = cg2 * 3;
        int nA = ng2 * 2, nB = nA + 1;
        float acc2[2][3];
#pragma unroll
        for (int cc = 0; cc < 3; ++cc) {
            int c = col0 + cc;
            float bb = (c < N_CLS) ? b2[c] : 0.f;
            acc2[0][cc] = bb; acc2[1][cc] = bb;
        }
        for (int j4 = 0; j4 < H_DIM / 4; ++j4) {
            float4 z0 = *(const float4*)&zs[nA][j4 * 4];
            float4 z1 = *(const float4*)&zs[nB][j4 * 4];
#pragma unroll
            for (int cc = 0; cc < 3; ++cc) {
                float4 w = *(const float4*)&W2t[(size_t)(col0 + cc) * H_DIM + j4 * 4];
                acc2[0][cc] += z0.x * w.x + z0.y * w.y + z0.z * w.z + z0.w * w.w;
                acc2[1][cc] += z1.x * w.x + z1.y * w.y + z1.z * w.z + z1.w * w.w;
            }
        }
#pragma unroll
        for (int n = 0; n < 2; ++n)
#pragma unroll
            for (int cc = 0; cc < 3; ++cc) {
                int c = col0 + cc;
                int gn = node0 + nA + n;
                if (c < N_CLS && gn < n_nodes)
                    out[(size_t)gn * N_CLS + c] = acc2[n][cc];
            }
    }
}

// ---------------- launch ----------------

static inline size_t align_up(size_t v, size_t a) { return (v + a - 1) & ~(a - 1); }

extern "C" void kernel_launch(void* const* d_in, const int* in_sizes, int n_in,
                              void* d_out, int out_size, void* d_ws, size_t ws_size,
                              hipStream_t stream) {
    const float* x   = (const float*)d_in[0];
    const int*   src = (const int*)d_in[1];
    const int*   dst = (const int*)d_in[2];
    const float* W1  = (const float*)d_in[3];
    const float* b1  = (const float*)d_in[4];
    const float* W2  = (const float*)d_in[5];
    const float* b2  = (const float*)d_in[6];
    float* out = (float*)d_out;

    char* p = (char*)d_ws;
    size_t off = 0;
    int* deg = (int*)(p + off);           off = align_up(off + N_NODES * 4, 256);
    int* row_ptr = (int*)(p + off);       off = align_up(off + (N_NODES + 1) * 4, 256);
    int* fill = (int*)(p + off);          off = align_up(off + N_NODES * 4, 256);
    float* norm = (float*)(p + off);      off = align_up(off + N_NODES * 4, 256);
    float2* ew = (float2*)(p + off);      off = align_up(off + N_EDGES * 8, 256);
    float* hA = (float*)(p + off);        off = align_up(off + (size_t)N_NODES * D_DATA * 4, 256);
    float* hB = (float*)(p + off);        off = align_up(off + (size_t)N_NODES * D_DATA * 4, 256);
    (void)ws_size;
    float* W2t = (float*)fill;   // fill is dead after scatter_kernel

    hipMemsetAsync(deg, 0, N_NODES * 4, stream);
    hipMemsetAsync(fill, 0, N_NODES * 4, stream);

    int eb = (N_EDGES + 255) / 256;
    deg_kernel<<<eb, 256, 0, stream>>>(dst, deg, N_EDGES);
    scan_norm_kernel<<<1, 1024, 0, stream>>>(deg, row_ptr, norm, N_NODES);
    scatter_kernel<<<eb, 256, 0, stream>>>(src, dst, norm, row_ptr, fill, ew, N_EDGES);
    transpose_w2_kernel<<<(48 * H_DIM + 255) / 256, 256, 0, stream>>>(W2, W2t);

    int pb = N_NODES / 4;   // 100000 % 4 == 0; 4 waves (nodes) per block
    const float* hin = x;
    float* houts[2] = {hA, hB};
    for (int k = 0; k < K_STEPS; ++k) {
        float* ho = houts[k & 1];
        prop_kernel<<<pb, 256, 0, stream>>>(hin, x, row_ptr, ew, ho, N_NODES);
        hin = ho;
    }

    int mb = N_NODES / TN;
    mlp_kernel<<<mb, 256, 0, stream>>>(hin, W1, b1, W2t, b2, out, N_NODES);
}

// Round 4
// 959.890 us; speedup vs baseline: 1.9295x; 1.2240x over previous
//
#include <hip/hip_runtime.h>

// APPNP: K steps of D^{-1/2} A D^{-1/2} propagation + teleport, then MLP.
// CSR built once per call; per-edge weight folds (1-alpha)*norm[src]*norm[dst].
// R4: parallel 3-kernel scan (old single-block scan was 232 us @ 0.15% occ);
// prop gathers rows as float2 on lanes 0..49 (1 VMEM op per edge row).

#define N_NODES 100000
#define N_EDGES 800000
#define D_DATA  100
#define H_DIM   256
#define N_CLS   47
#define K_STEPS 10
#define ALPHA   0.1f

#define SCAN_NB    200   // blocks in the parallel scan
#define SCAN_CHUNK 500   // elements per block; 200*500 == N_NODES

// ---------------- CSR build ----------------

__global__ void deg_kernel(const int* __restrict__ dst, int* __restrict__ deg, int e) {
    int i = blockIdx.x * blockDim.x + threadIdx.x;
    if (i < e) atomicAdd(&deg[dst[i]], 1);
}

// pass 1: per-block sums of deg
__global__ __launch_bounds__(256) void scan_partial_kernel(
        const int* __restrict__ deg, int* __restrict__ partials) {
    __shared__ int red[256];
    int t = threadIdx.x;
    int base = blockIdx.x * SCAN_CHUNK;
    int s = 0;
    int i0 = 2 * t, i1 = 2 * t + 1;
    if (i0 < SCAN_CHUNK) s += deg[base + i0];
    if (i1 < SCAN_CHUNK) s += deg[base + i1];
    red[t] = s;
    __syncthreads();
    for (int off = 128; off > 0; off >>= 1) {
        if (t < off) red[t] += red[t + off];
        __syncthreads();
    }
    if (t == 0) partials[blockIdx.x] = red[0];
}

// pass 2: single block scans the 200 partials (exclusive)
__global__ __launch_bounds__(256) void scan_top_kernel(
        const int* __restrict__ partials, int* __restrict__ pofs,
        int* __restrict__ row_ptr) {
    __shared__ int s[256];
    int t = threadIdx.x;
    s[t] = (t < SCAN_NB) ? partials[t] : 0;
    __syncthreads();
    for (int off = 1; off < 256; off <<= 1) {
        int v = (t >= off) ? s[t - off] : 0;
        __syncthreads();
        s[t] += v;
        __syncthreads();
    }
    if (t < SCAN_NB) pofs[t] = s[t] - partials[t];   // exclusive
    if (t == 0) row_ptr[N_NODES] = N_EDGES;          // total degree is fixed
}

// pass 3: block-local exclusive scan + emit row_ptr and norm
__global__ __launch_bounds__(256) void scan_emit_kernel(
        const int* __restrict__ deg, const int* __restrict__ pofs,
        int* __restrict__ row_ptr, float* __restrict__ norm) {
    __shared__ int s[256];
    int t = threadIdx.x;
    int base = blockIdx.x * SCAN_CHUNK;
    int i0 = 2 * t, i1 = 2 * t + 1;
    int d0 = (i0 < SCAN_CHUNK) ? deg[base + i0] : 0;
    int d1 = (i1 < SCAN_CHUNK) ? deg[base + i1] : 0;
    s[t] = d0 + d1;
    __syncthreads();
    for (int off = 1; off < 256; off <<= 1) {
        int v = (t >= off) ? s[t - off] : 0;
        __syncthreads();
        s[t] += v;
        __syncthreads();
    }
    int p = s[t] - (d0 + d1) + pofs[blockIdx.x];   // exclusive + block offset
    if (i0 < SCAN_CHUNK) {
        row_ptr[base + i0] = p;
        norm[base + i0] = rsqrtf((float)max(d0, 1));
    }
    if (i1 < SCAN_CHUNK) {
        row_ptr[base + i1] = p + d0;
        norm[base + i1] = rsqrtf((float)max(d1, 1));
    }
}

__global__ void scatter_kernel(const int* __restrict__ src, const int* __restrict__ dst,
                               const float* __restrict__ norm,
                               const int* __restrict__ row_ptr, int* __restrict__ fill,
                               float2* __restrict__ ew, int e) {
    int i = blockIdx.x * blockDim.x + threadIdx.x;
    if (i < e) {
        int d = dst[i], s = src[i];
        int pos = row_ptr[d] + atomicAdd(&fill[d], 1);
        float w = (1.0f - ALPHA) * norm[s] * norm[d];
        ew[pos] = make_float2(w, __int_as_float(s));
    }
}

// W2 [256][47] -> W2t [48][256], zero-padded col 47.
__global__ void transpose_w2_kernel(const float* __restrict__ W2, float* __restrict__ W2t) {
    int idx = blockIdx.x * blockDim.x + threadIdx.x;
    if (idx < 48 * H_DIM) {
        int c = idx >> 8;
        int j = idx & (H_DIM - 1);
        W2t[c * H_DIM + j] = (c < N_CLS) ? W2[j * N_CLS + c] : 0.f;
    }
}

// ---------------- propagation ----------------
// One wave per node; lanes 0..49 each hold a float2 of the 100-float row
// (one 8B gather instruction covers the whole 400B row). x8 unroll keeps
// 8 row-gathers in flight.

__global__ __launch_bounds__(256) void prop_kernel(
        const float* __restrict__ hin, const float* __restrict__ x,
        const int* __restrict__ row_ptr, const float2* __restrict__ ew,
        float* __restrict__ hout, int n_nodes) {
    int lane = threadIdx.x & 63;
    int node = __builtin_amdgcn_readfirstlane(blockIdx.x * 4 + (threadIdx.x >> 6));
    if (node >= n_nodes) return;
    int beg = __builtin_amdgcn_readfirstlane(row_ptr[node]);
    int end = __builtin_amdgcn_readfirstlane(row_ptr[node + 1]);
    bool act = lane < (D_DATA / 2);   // 50 lanes carry the row
    float ax = 0.f, ay = 0.f, bx = 0.f, by = 0.f;
    float cx = 0.f, cy = 0.f, dx = 0.f, dy = 0.f;
    int e = beg;
    for (; e + 8 <= end; e += 8) {
        float2 p[8];
#pragma unroll
        for (int j = 0; j < 8; ++j) p[j] = ew[e + j];          // uniform -> s_load
        float2 v[8];
#pragma unroll
        for (int j = 0; j < 8; ++j) {
            const float2* r = (const float2*)(hin + (size_t)__float_as_int(p[j].y) * D_DATA);
            v[j] = act ? r[lane] : make_float2(0.f, 0.f);
        }
        ax += p[0].x * v[0].x; ay += p[0].x * v[0].y;
        bx += p[1].x * v[1].x; by += p[1].x * v[1].y;
        cx += p[2].x * v[2].x; cy += p[2].x * v[2].y;
        dx += p[3].x * v[3].x; dy += p[3].x * v[3].y;
        ax += p[4].x * v[4].x; ay += p[4].x * v[4].y;
        bx += p[5].x * v[5].x; by += p[5].x * v[5].y;
        cx += p[6].x * v[6].x; cy += p[6].x * v[6].y;
        dx += p[7].x * v[7].x; dy += p[7].x * v[7].y;
    }
    for (; e < end; ++e) {
        float2 p = ew[e];
        const float2* r = (const float2*)(hin + (size_t)__float_as_int(p.y) * D_DATA);
        float2 v = act ? r[lane] : make_float2(0.f, 0.f);
        ax += p.x * v.x; ay += p.x * v.y;
    }
    if (act) {
        float sx = (ax + bx) + (cx + dx);
        float sy = (ay + by) + (cy + dy);
        const float2* x2 = (const float2*)(x + (size_t)node * D_DATA);
        float2 xv = x2[lane];
        float2 o;
        o.x = sx + ALPHA * xv.x;
        o.y = sy + ALPHA * xv.y;
        ((float2*)(hout + (size_t)node * D_DATA))[lane] = o;
    }
}

// ---------------- fused MLP ----------------
// Block = 256 threads, 32 nodes. Phase 1: thread (cg=t&63 -> 4 cols,
// ng=t>>6 -> 8 nodes); h rows wave-uniform -> scalar loads; W1 pipelined.
// Phase 2: thread (cg2=t>>4 -> 3 cols, ng2=t&15 -> 2 nodes).

#define TN 32
#define HP 260

__global__ __launch_bounds__(256, 4) void mlp_kernel(
        const float* __restrict__ h,
        const float* __restrict__ W1, const float* __restrict__ b1,
        const float* __restrict__ W2t, const float* __restrict__ b2,
        float* __restrict__ out, int n_nodes) {
    __shared__ float zs[TN][HP];   // 32.5 KB -> 4 blocks/CU
    int tid = threadIdx.x;
    int node0 = blockIdx.x * TN;

    // ---- phase 1: z = relu(h @ W1 + b1) ----
    {
        int cg = tid & 63;
        int ng = tid >> 6;
        const float4* hrow[8];
#pragma unroll
        for (int i = 0; i < 8; ++i) {
            int r = __builtin_amdgcn_readfirstlane(node0 + ng * 8 + i);
            hrow[i] = (const float4*)(h + (size_t)r * D_DATA);
        }
        float acc[8][4];
        float4 bv = *(const float4*)(b1 + 4 * cg);
#pragma unroll
        for (int i = 0; i < 8; ++i) {
            acc[i][0] = bv.x; acc[i][1] = bv.y; acc[i][2] = bv.z; acc[i][3] = bv.w;
        }
        float4 wv[4], wn[4];
#pragma unroll
        for (int k = 0; k < 4; ++k)
            wv[k] = *(const float4*)&W1[(size_t)k * H_DIM + 4 * cg];
        for (int d4 = 0; d4 < D_DATA / 4; ++d4) {
            if (d4 + 1 < D_DATA / 4) {
#pragma unroll
                for (int k = 0; k < 4; ++k)
                    wn[k] = *(const float4*)&W1[(size_t)((d4 + 1) * 4 + k) * H_DIM + 4 * cg];
            }
            float4 hv[8];
#pragma unroll
            for (int i = 0; i < 8; ++i) hv[i] = hrow[i][d4];   // scalar pipe
#pragma unroll
            for (int i = 0; i < 8; ++i) {
                acc[i][0] += hv[i].x * wv[0].x + hv[i].y * wv[1].x + hv[i].z * wv[2].x + hv[i].w * wv[3].x;
                acc[i][1] += hv[i].x * wv[0].y + hv[i].y * wv[1].y + hv[i].z * wv[2].y + hv[i].w * wv[3].y;
                acc[i][2] += hv[i].x * wv[0].z + hv[i].y * wv[1].z + hv[i].z * wv[2].z + hv[i].w * wv[3].z;
                acc[i][3] += hv[i].x * wv[0].w + hv[i].y * wv[1].w + hv[i].z * wv[2].w + hv[i].w * wv[3].w;
            }
#pragma unroll
            for (int k = 0; k < 4; ++k) wv[k] = wn[k];
        }
#pragma unroll
        for (int i = 0; i < 8; ++i) {
            float4 t;
            t.x = fmaxf(acc[i][0], 0.f); t.y = fmaxf(acc[i][1], 0.f);
            t.z = fmaxf(acc[i][2], 0.f); t.w = fmaxf(acc[i][3], 0.f);
            *(float4*)&zs[ng * 8 + i][4 * cg] = t;
        }
    }
    __syncthreads();

    // ---- phase 2: out = z @ W2 + b2 ----
    {
        int cg2 = tid >> 4;
        int ng2 = tid & 15;
        int col0 = cg2 * 3;
        int nA = ng2 * 2, nB = nA + 1;
        float acc2[2][3];
#pragma unroll
        for (int cc = 0; cc < 3; ++cc) {
            int c = col0 + cc;
            float bb = (c < N_CLS) ? b2[c] : 0.f;
            acc2[0][cc] = bb; acc2[1][cc] = bb;
        }
        for (int j4 = 0; j4 < H_DIM / 4; ++j4) {
            float4 z0 = *(const float4*)&zs[nA][j4 * 4];
            float4 z1 = *(const float4*)&zs[nB][j4 * 4];
#pragma unroll
            for (int cc = 0; cc < 3; ++cc) {
                float4 w = *(const float4*)&W2t[(size_t)(col0 + cc) * H_DIM + j4 * 4];
                acc2[0][cc] += z0.x * w.x + z0.y * w.y + z0.z * w.z + z0.w * w.w;
                acc2[1][cc] += z1.x * w.x + z1.y * w.y + z1.z * w.z + z1.w * w.w;
            }
        }
#pragma unroll
        for (int n = 0; n < 2; ++n)
#pragma unroll
            for (int cc = 0; cc < 3; ++cc) {
                int c = col0 + cc;
                int gn = node0 + nA + n;
                if (c < N_CLS && gn < n_nodes)
                    out[(size_t)gn * N_CLS + c] = acc2[n][cc];
            }
    }
}

// ---------------- launch ----------------

static inline size_t align_up(size_t v, size_t a) { return (v + a - 1) & ~(a - 1); }

extern "C" void kernel_launch(void* const* d_in, const int* in_sizes, int n_in,
                              void* d_out, int out_size, void* d_ws, size_t ws_size,
                              hipStream_t stream) {
    const float* x   = (const float*)d_in[0];
    const int*   src = (const int*)d_in[1];
    const int*   dst = (const int*)d_in[2];
    const float* W1  = (const float*)d_in[3];
    const float* b1  = (const float*)d_in[4];
    const float* W2  = (const float*)d_in[5];
    const float* b2  = (const float*)d_in[6];
    float* out = (float*)d_out;

    char* p = (char*)d_ws;
    size_t off = 0;
    int* deg = (int*)(p + off);           off = align_up(off + N_NODES * 4, 256);
    int* row_ptr = (int*)(p + off);       off = align_up(off + (N_NODES + 1) * 4, 256);
    int* fill = (int*)(p + off);          off = align_up(off + N_NODES * 4, 256);
    float* norm = (float*)(p + off);      off = align_up(off + N_NODES * 4, 256);
    int* partials = (int*)(p + off);      off = align_up(off + SCAN_NB * 4, 256);
    int* pofs = (int*)(p + off);          off = align_up(off + SCAN_NB * 4, 256);
    float2* ew = (float2*)(p + off);      off = align_up(off + N_EDGES * 8, 256);
    float* hA = (float*)(p + off);        off = align_up(off + (size_t)N_NODES * D_DATA * 4, 256);
    float* hB = (float*)(p + off);        off = align_up(off + (size_t)N_NODES * D_DATA * 4, 256);
    (void)ws_size;
    float* W2t = (float*)fill;   // fill is dead after scatter_kernel

    hipMemsetAsync(deg, 0, N_NODES * 4, stream);
    hipMemsetAsync(fill, 0, N_NODES * 4, stream);

    int eb = (N_EDGES + 255) / 256;
    deg_kernel<<<eb, 256, 0, stream>>>(dst, deg, N_EDGES);
    scan_partial_kernel<<<SCAN_NB, 256, 0, stream>>>(deg, partials);
    scan_top_kernel<<<1, 256, 0, stream>>>(partials, pofs, row_ptr);
    scan_emit_kernel<<<SCAN_NB, 256, 0, stream>>>(deg, pofs, row_ptr, norm);
    scatter_kernel<<<eb, 256, 0, stream>>>(src, dst, norm, row_ptr, fill, ew, N_EDGES);
    transpose_w2_kernel<<<(48 * H_DIM + 255) / 256, 256, 0, stream>>>(W2, W2t);

    int pb = N_NODES / 4;   // 4 waves (nodes) per block
    const float* hin = x;
    float* houts[2] = {hA, hB};
    for (int k = 0; k < K_STEPS; ++k) {
        float* ho = houts[k & 1];
        prop_kernel<<<pb, 256, 0, stream>>>(hin, x, row_ptr, ew, ho, N_NODES);
        hin = ho;
    }

    int mb = N_NODES / TN;
    mlp_kernel<<<mb, 256, 0, stream>>>(hin, W1, b1, W2t, b2, out, N_NODES);
}